// Round 6
// baseline (579.439 us; speedup 1.0000x reference)
//
#include <hip/hip_runtime.h>

#define N_VNS   8192
#define N_CNS   4096
#define BATCH   1024
#define NUM_ITER 20
#define MAX_E   24576           // == 6 * N_CNS, fixed 6-slot-per-CN SoA layout
#define PHI_MIN 8.5e-08f
#define PHI_MAX 16.635532f
#define LOG2E   1.44269504088896f
#define LN2     0.693147180559945f
// scaled-domain clip bounds: [PHI_MIN*log2e, PHI_MAX*log2e]
#define YMIN2   1.2263e-07f
#define YMAX2   24.0f
#define LDS_BYTES ((MAX_E + N_CNS) * 4)

// Scaled phi: g(y) = log2((2^y+1)/(2^y-1)).  Whole decoder runs in the
// log2-scaled domain (all messages/sums are linear in scale), so the
// x*log2e / *ln2 multiplies amortize to one scale at entry + one at exit.
// e-1 clamped to 2^-23 to mimic reference f32 rounding at the PHI_MIN edge.
__device__ __forceinline__ float phi2_f(float y) {
    y = fminf(fmaxf(y, YMIN2), YMAX2);              // v_med3_f32
    float e = __builtin_amdgcn_exp2f(y);
    float em1 = fmaxf(e - 1.0f, 1.1920929e-07f);
    return __builtin_amdgcn_logf((e + 1.0f) * __builtin_amdgcn_rcpf(em1));
}

// ---------- setup kernels (run once per launch, ~10 us total) ----------

__global__ void count_edges(const int* __restrict__ vn_con, const int* __restrict__ cn_con,
                            int E, int* __restrict__ vn_cnt, int* __restrict__ cn_cnt) {
    int e = blockIdx.x * 256 + threadIdx.x;
    if (e < E) {
        atomicAdd(&vn_cnt[vn_con[e]], 1);
        atomicAdd(&cn_cnt[cn_con[e]], 1);
    }
}

__global__ void scan_excl(const int* __restrict__ cnt, int n, int* __restrict__ ptr) {
    __shared__ int sh[1024];
    int carry = 0;
    if (threadIdx.x == 0) ptr[0] = 0;
    for (int base = 0; base < n; base += 1024) {
        int i = base + (int)threadIdx.x;
        int v = (i < n) ? cnt[i] : 0;
        sh[threadIdx.x] = v;
        __syncthreads();
        for (int off = 1; off < 1024; off <<= 1) {
            int add = ((int)threadIdx.x >= off) ? sh[threadIdx.x - off] : 0;
            __syncthreads();
            sh[threadIdx.x] += add;
            __syncthreads();
        }
        if (i < n) ptr[i + 1] = carry + sh[threadIdx.x];
        carry += sh[1023];
        __syncthreads();
    }
}

__global__ void fill_vn(const int* __restrict__ vn_con, int E,
                        const int* __restrict__ vn_ptr, int* __restrict__ vn_fill,
                        int* __restrict__ vn_eids) {
    int e = blockIdx.x * 256 + threadIdx.x;
    if (e < E) {
        int v = vn_con[e];
        int slot = atomicAdd(&vn_fill[v], 1);
        vn_eids[vn_ptr[v] + slot] = e;
    }
}

// deterministic CSR: sort each vn's (<=3) edge ids ascending, then pack
// vn_pack[v][k] = qslot | (cn << 15); qslot = rank*N_CNS + cn (SoA), where
// rank = eid - cn_ptr[cn] (edge's rank within its CN; edges sorted by cn).
// Pad slots (rank >= deg) stay +0.0 forever. 0xFFFFFFFF sentinel past degree.
__global__ void sort_pack_vn(const int* __restrict__ vn_ptr, int* __restrict__ vn_eids,
                             const int* __restrict__ cn_con, const int* __restrict__ cn_ptr,
                             unsigned* __restrict__ vn_pack) {
    int v = blockIdx.x * 256 + threadIdx.x;
    if (v >= N_VNS) return;
    int s = vn_ptr[v], n = vn_ptr[v + 1] - s;
    for (int i = 1; i < n; ++i) {
        int key = vn_eids[s + i];
        int j = i - 1;
        while (j >= 0 && vn_eids[s + j] > key) { vn_eids[s + j + 1] = vn_eids[s + j]; --j; }
        vn_eids[s + j + 1] = key;
    }
    for (int k = 0; k < 3; ++k) {
        unsigned p = 0xFFFFFFFFu;
        if (k < n) {
            int eid = vn_eids[s + k];
            int cn = cn_con[eid];
            unsigned rank = (unsigned)(eid - cn_ptr[cn]);
            p = (rank * N_CNS + (unsigned)cn) | ((unsigned)cn << 15);
        }
        vn_pack[v * 3 + k] = p;
    }
}

// ---------- the whole decode: one block per batch element ----------
// LDS: q_soa[6][N_CNS] : q_e = sgn(t_e)*phi2(|t_e|), phi-domain VN->CN msgs.
//                        WRITE-ONLY from VN phase (VN keeps its own copies in
//                        VGPRs), READ-ONLY in CN phase via 6 stride-1
//                        conflict-free ds_read_b32.
//      psum[N_CNS]     : sum_e phi2(|t_e|), CN sign-parity in bit 31.
// CN phase: branchless, no transcendentals. VN phase: 2 phi/edge (minimum).

__global__ __launch_bounds__(1024, 4) void decode(const float* __restrict__ llr_ch,
                                                  float* __restrict__ out,
                                                  const unsigned* __restrict__ vn_pack) {
    extern __shared__ unsigned lds[];
    unsigned* q = lds;                  // [6][N_CNS]
    unsigned* psum = lds + MAX_E;       // [N_CNS]

    int b = blockIdx.x, tid = threadIdx.x;
    const float* llr_row = llr_ch + (size_t)b * N_VNS;

    float llr[8];
    unsigned pk[8][3];
    unsigned qr[8][3];                  // register-resident q for own edges
    #pragma unroll
    for (int i = 0; i < 8; ++i) {
        int v = i * 1024 + tid;
        llr[i] = -llr_row[v] * LOG2E;   // enter scaled domain
        #pragma unroll
        for (int k = 0; k < 3; ++k) pk[i][k] = vn_pack[v * 3 + k];
    }

    // zero all q slots (pads must stay +0.0), then initial t_e = llr[vn_e]
    #pragma unroll
    for (int k = 0; k < 24; ++k) q[k * 1024 + tid] = 0u;
    __syncthreads();
    #pragma unroll
    for (int i = 0; i < 8; ++i) {
        unsigned nq = __float_as_uint(phi2_f(fabsf(llr[i]))) |
                      (__float_as_uint(llr[i]) & 0x80000000u);
        #pragma unroll
        for (int k = 0; k < 3; ++k)
            if (pk[i][k] != 0xFFFFFFFFu) { qr[i][k] = nq; q[pk[i][k] & 0x7FFFu] = nq; }
    }
    __syncthreads();

    for (int it = 0; it < NUM_ITER; ++it) {
        // ---- CN phase: psum[c] = (+/-) sum_k |q_k|, parity in bit 31 ----
        #pragma unroll
        for (int i = 0; i < 4; ++i) {
            int c = i * 1024 + tid;
            unsigned q0 = q[c];
            unsigned q1 = q[N_CNS + c];
            unsigned q2 = q[2 * N_CNS + c];
            unsigned q3 = q[3 * N_CNS + c];
            unsigned q4 = q[4 * N_CNS + c];
            unsigned q5 = q[5 * N_CNS + c];
            unsigned par = q0 ^ q1 ^ q2 ^ q3 ^ q4 ^ q5;
            float ps = __uint_as_float(q0 & 0x7FFFFFFFu);
            ps += __uint_as_float(q1 & 0x7FFFFFFFu);
            ps += __uint_as_float(q2 & 0x7FFFFFFFu);
            ps += __uint_as_float(q3 & 0x7FFFFFFFu);
            ps += __uint_as_float(q4 & 0x7FFFFFFFu);
            ps += __uint_as_float(q5 & 0x7FFFFFFFu);
            psum[c] = __float_as_uint(ps) | (par & 0x80000000u);
        }
        __syncthreads();
        if (it == NUM_ITER - 1) break;

        // ---- VN phase: msg_e = sgn*phi2(|ps|-|q_e|); new q = phi2(ns-msg) ----
        #pragma unroll
        for (int i = 0; i < 8; ++i) {
            float ns = llr[i];
            float msg[3];
            #pragma unroll
            for (int k = 0; k < 3; ++k) {
                msg[k] = 0.f;
                unsigned p = pk[i][k];
                if (p != 0xFFFFFFFFu) {
                    unsigned qb = qr[i][k];
                    unsigned pb = psum[p >> 15];
                    float a = __uint_as_float(pb & 0x7FFFFFFFu) -
                              __uint_as_float(qb & 0x7FFFFFFFu);
                    float m = __uint_as_float(__float_as_uint(phi2_f(a)) ^
                                              ((qb ^ pb) & 0x80000000u));
                    msg[k] = m;
                    ns += m;
                }
            }
            #pragma unroll
            for (int k = 0; k < 3; ++k) {
                unsigned p = pk[i][k];
                if (p != 0xFFFFFFFFu) {
                    float tnew = ns - msg[k];
                    unsigned nq = __float_as_uint(phi2_f(fabsf(tnew))) |
                                  (__float_as_uint(tnew) & 0x80000000u);
                    qr[i][k] = nq;
                    q[p & 0x7FFFu] = nq;
                }
            }
        }
        __syncthreads();
    }

    // ---- marginalization: out[b][v] = -(llr + sum_e msg_e) / log2e ----
    float* orow = out + (size_t)b * N_VNS;
    #pragma unroll
    for (int i = 0; i < 8; ++i) {
        float ns = llr[i];
        #pragma unroll
        for (int k = 0; k < 3; ++k) {
            unsigned p = pk[i][k];
            if (p != 0xFFFFFFFFu) {
                unsigned qb = qr[i][k];
                unsigned pb = psum[p >> 15];
                float a = __uint_as_float(pb & 0x7FFFFFFFu) -
                          __uint_as_float(qb & 0x7FFFFFFFu);
                ns += __uint_as_float(__float_as_uint(phi2_f(a)) ^
                                      ((qb ^ pb) & 0x80000000u));
            }
        }
        orow[i * 1024 + tid] = -ns * LN2;   // leave scaled domain
    }
}

extern "C" void kernel_launch(void* const* d_in, const int* in_sizes, int n_in,
                              void* d_out, int out_size, void* d_ws, size_t ws_size,
                              hipStream_t stream) {
    const float* llr_ch = (const float*)d_in[0];
    const int* vn_con = (const int*)d_in[1];
    const int* cn_con = (const int*)d_in[2];
    int E = in_sizes[1];
    float* out = (float*)d_out;

    char* ws = (char*)d_ws;
    size_t off = 0;
    auto alloc = [&](size_t bytes) -> void* {
        void* ptr = ws + off;
        off = (off + bytes + 255) & ~(size_t)255;
        return ptr;
    };
    int* vn_ptr  = (int*)alloc((N_VNS + 1) * 4);
    int* cn_ptr  = (int*)alloc((N_CNS + 1) * 4);
    int* vn_cnt  = (int*)alloc(N_VNS * 4);
    int* cn_cnt  = (int*)alloc(N_CNS * 4);
    int* vn_fill = (int*)alloc(N_VNS * 4);
    int* vn_eids = (int*)alloc((size_t)E * 4);
    unsigned* vn_pack = (unsigned*)alloc((size_t)N_VNS * 3 * 4);

    hipMemsetAsync(vn_cnt, 0, N_VNS * 4, stream);
    hipMemsetAsync(cn_cnt, 0, N_CNS * 4, stream);
    hipMemsetAsync(vn_fill, 0, N_VNS * 4, stream);

    count_edges<<<(E + 255) / 256, 256, 0, stream>>>(vn_con, cn_con, E, vn_cnt, cn_cnt);
    scan_excl<<<1, 1024, 0, stream>>>(vn_cnt, N_VNS, vn_ptr);
    scan_excl<<<1, 1024, 0, stream>>>(cn_cnt, N_CNS, cn_ptr);
    fill_vn<<<(E + 255) / 256, 256, 0, stream>>>(vn_con, E, vn_ptr, vn_fill, vn_eids);
    sort_pack_vn<<<(N_VNS + 255) / 256, 256, 0, stream>>>(vn_ptr, vn_eids, cn_con, cn_ptr,
                                                          vn_pack);

    static bool attr_set = false;
    if (!attr_set) {
        hipFuncSetAttribute((const void*)decode,
                            hipFuncAttributeMaxDynamicSharedMemorySize, LDS_BYTES);
        attr_set = true;
    }
    decode<<<BATCH, 1024, LDS_BYTES, stream>>>(llr_ch, out, vn_pack);
}

// Round 7
// 542.257 us; speedup vs baseline: 1.0686x; 1.0686x over previous
//
#include <hip/hip_runtime.h>

#define N_VNS   8192
#define N_CNS   4096
#define BATCH   1024
#define NUM_ITER 20
#define MAX_E   24576           // == 6 * N_CNS, fixed 6-slot-per-CN SoA layout
#define PHI_MIN 8.5e-08f
#define PHI_MAX 16.635532f
#define LOG2E   1.44269504088896f
#define LN2     0.693147180559945f
// scaled-domain clip bounds: [PHI_MIN*log2e, PHI_MAX*log2e]
#define YMIN2   1.2263e-07f
#define YMAX2   24.0f
#define LDS_BYTES ((MAX_E + N_CNS) * 4)

// Scaled phi: g(y) = log2((2^y+1)/(2^y-1)) -- decoder runs in the log2-scaled
// domain (messages are linear in scale): scale at entry, descale at exit.
// e-1 clamped to 2^-23 to mimic reference f32 rounding at the PHI_MIN edge.
__device__ __forceinline__ float phi2_f(float y) {
    y = fminf(fmaxf(y, YMIN2), YMAX2);              // v_med3_f32
    float e = __builtin_amdgcn_exp2f(y);
    float em1 = fmaxf(e - 1.0f, 1.1920929e-07f);
    return __builtin_amdgcn_logf((e + 1.0f) * __builtin_amdgcn_rcpf(em1));
}

// ---------- setup kernels (run once per launch, ~10 us total) ----------

__global__ void count_edges(const int* __restrict__ vn_con, const int* __restrict__ cn_con,
                            int E, int* __restrict__ vn_cnt, int* __restrict__ cn_cnt) {
    int e = blockIdx.x * 256 + threadIdx.x;
    if (e < E) {
        atomicAdd(&vn_cnt[vn_con[e]], 1);
        atomicAdd(&cn_cnt[cn_con[e]], 1);
    }
}

__global__ void scan_excl(const int* __restrict__ cnt, int n, int* __restrict__ ptr) {
    __shared__ int sh[1024];
    int carry = 0;
    if (threadIdx.x == 0) ptr[0] = 0;
    for (int base = 0; base < n; base += 1024) {
        int i = base + (int)threadIdx.x;
        int v = (i < n) ? cnt[i] : 0;
        sh[threadIdx.x] = v;
        __syncthreads();
        for (int off = 1; off < 1024; off <<= 1) {
            int add = ((int)threadIdx.x >= off) ? sh[threadIdx.x - off] : 0;
            __syncthreads();
            sh[threadIdx.x] += add;
            __syncthreads();
        }
        if (i < n) ptr[i + 1] = carry + sh[threadIdx.x];
        carry += sh[1023];
        __syncthreads();
    }
}

__global__ void fill_vn(const int* __restrict__ vn_con, int E,
                        const int* __restrict__ vn_ptr, int* __restrict__ vn_fill,
                        int* __restrict__ vn_eids) {
    int e = blockIdx.x * 256 + threadIdx.x;
    if (e < E) {
        int v = vn_con[e];
        int slot = atomicAdd(&vn_fill[v], 1);
        vn_eids[vn_ptr[v] + slot] = e;
    }
}

// deterministic CSR: sort each vn's (<=3) edge ids ascending, then pack the
// three 16-bit qslots into a uint2:  qslot = rank*N_CNS + cn  (SoA index;
// cn recoverable as qslot & 0xFFF since N_CNS = 2^12).  rank = eid -
// cn_ptr[cn].  Sentinel 0xFFFF past degree; pad slots stay +0.0 forever.
__global__ void sort_pack_vn(const int* __restrict__ vn_ptr, int* __restrict__ vn_eids,
                             const int* __restrict__ cn_con, const int* __restrict__ cn_ptr,
                             uint2* __restrict__ vn_pack) {
    int v = blockIdx.x * 256 + threadIdx.x;
    if (v >= N_VNS) return;
    int s = vn_ptr[v], n = vn_ptr[v + 1] - s;
    for (int i = 1; i < n; ++i) {
        int key = vn_eids[s + i];
        int j = i - 1;
        while (j >= 0 && vn_eids[s + j] > key) { vn_eids[s + j + 1] = vn_eids[s + j]; --j; }
        vn_eids[s + j + 1] = key;
    }
    unsigned sl[3];
    for (int k = 0; k < 3; ++k) {
        sl[k] = 0xFFFFu;
        if (k < n) {
            int eid = vn_eids[s + k];
            int cn = cn_con[eid];
            unsigned rank = (unsigned)(eid - cn_ptr[cn]);
            sl[k] = rank * N_CNS + (unsigned)cn;
        }
    }
    vn_pack[v] = make_uint2(sl[0] | (sl[1] << 16), sl[2] | 0xFFFF0000u);
}

// ---------- the whole decode: one block per batch element ----------
// LDS: q_soa[6][N_CNS] : q_e = sgn(t_e)*phi2(|t_e|).  WRITE-only from VN
//                        (VN keeps own copies in VGPRs), READ-only in CN via
//                        stride-1 conflict-free ds_read_b32.
//      psum[N_CNS]     : sum_e phi2(|t_e|), CN sign-parity in bit 31.
// CN phase: branchless, no transcendentals. VN phase: 2 phi/edge (minimum).
// waves_per_eu(4,4): occupancy is LDS-capped at 16 waves/CU anyway; give the
// allocator the full 128-VGPR budget so per-thread state does NOT spill.

__global__ __launch_bounds__(1024)
__attribute__((amdgpu_waves_per_eu(4, 4)))
void decode(const float* __restrict__ llr_ch, float* __restrict__ out,
            const uint2* __restrict__ vn_pack) {
    extern __shared__ unsigned lds[];
    unsigned* q = lds;                  // [6][N_CNS]
    unsigned* psum = lds + MAX_E;       // [N_CNS]

    int b = blockIdx.x, tid = threadIdx.x;
    const float* llr_row = llr_ch + (size_t)b * N_VNS;

    float llr[8];
    uint2 pw[8];                        // packed 3x16-bit qslots per VN
    unsigned qr[8][3];                  // register-resident q for own edges
    #pragma unroll
    for (int i = 0; i < 8; ++i) {
        int v = i * 1024 + tid;
        llr[i] = -llr_row[v] * LOG2E;   // enter scaled domain
        pw[i] = vn_pack[v];
    }

    // zero all q slots (pads must stay +0.0), then initial t_e = llr[vn_e]
    #pragma unroll
    for (int k = 0; k < 24; ++k) q[k * 1024 + tid] = 0u;
    __syncthreads();
    #pragma unroll
    for (int i = 0; i < 8; ++i) {
        unsigned nq = __float_as_uint(phi2_f(fabsf(llr[i]))) |
                      (__float_as_uint(llr[i]) & 0x80000000u);
        #pragma unroll
        for (int k = 0; k < 3; ++k) {
            unsigned s = (k == 0) ? (pw[i].x & 0xFFFFu)
                       : (k == 1) ? (pw[i].x >> 16)
                                  : (pw[i].y & 0xFFFFu);
            if (s != 0xFFFFu) { qr[i][k] = nq; q[s] = nq; }
        }
    }
    __syncthreads();

    for (int it = 0; it < NUM_ITER; ++it) {
        // ---- CN phase: psum[c] = (+/-) sum_k |q_k|, parity in bit 31 ----
        #pragma unroll
        for (int i = 0; i < 4; ++i) {
            int c = i * 1024 + tid;
            unsigned q0 = q[c];
            unsigned q1 = q[N_CNS + c];
            unsigned q2 = q[2 * N_CNS + c];
            unsigned q3 = q[3 * N_CNS + c];
            unsigned q4 = q[4 * N_CNS + c];
            unsigned q5 = q[5 * N_CNS + c];
            unsigned par = q0 ^ q1 ^ q2 ^ q3 ^ q4 ^ q5;
            // VOP3 abs input modifiers make the |.| free on each add
            float ps = fabsf(__uint_as_float(q0)) + fabsf(__uint_as_float(q1));
            ps += fabsf(__uint_as_float(q2));
            ps += fabsf(__uint_as_float(q3));
            ps += fabsf(__uint_as_float(q4));
            ps += fabsf(__uint_as_float(q5));
            psum[c] = __float_as_uint(ps) | (par & 0x80000000u);
        }
        __syncthreads();
        if (it == NUM_ITER - 1) break;

        // ---- VN phase: msg_e = sgn*phi2(|ps|-|q_e|); new q = phi2(ns-msg) ----
        #pragma unroll
        for (int i = 0; i < 8; ++i) {
            float ns = llr[i];
            float msg[3];
            #pragma unroll
            for (int k = 0; k < 3; ++k) {
                msg[k] = 0.f;
                unsigned s = (k == 0) ? (pw[i].x & 0xFFFFu)
                           : (k == 1) ? (pw[i].x >> 16)
                                      : (pw[i].y & 0xFFFFu);
                if (s != 0xFFFFu) {
                    unsigned qb = qr[i][k];
                    unsigned pb = psum[s & 0xFFFu];
                    float a = fabsf(__uint_as_float(pb)) - fabsf(__uint_as_float(qb));
                    float m = __uint_as_float(__float_as_uint(phi2_f(a)) ^
                                              ((qb ^ pb) & 0x80000000u));
                    msg[k] = m;
                    ns += m;
                }
            }
            #pragma unroll
            for (int k = 0; k < 3; ++k) {
                unsigned s = (k == 0) ? (pw[i].x & 0xFFFFu)
                           : (k == 1) ? (pw[i].x >> 16)
                                      : (pw[i].y & 0xFFFFu);
                if (s != 0xFFFFu) {
                    float tnew = ns - msg[k];
                    unsigned nq = __float_as_uint(phi2_f(fabsf(tnew))) |
                                  (__float_as_uint(tnew) & 0x80000000u);
                    qr[i][k] = nq;
                    q[s] = nq;
                }
            }
        }
        __syncthreads();
    }

    // ---- marginalization: out[b][v] = -(llr + sum_e msg_e) / log2e ----
    float* orow = out + (size_t)b * N_VNS;
    #pragma unroll
    for (int i = 0; i < 8; ++i) {
        float ns = llr[i];
        #pragma unroll
        for (int k = 0; k < 3; ++k) {
            unsigned s = (k == 0) ? (pw[i].x & 0xFFFFu)
                       : (k == 1) ? (pw[i].x >> 16)
                                  : (pw[i].y & 0xFFFFu);
            if (s != 0xFFFFu) {
                unsigned qb = qr[i][k];
                unsigned pb = psum[s & 0xFFFu];
                float a = fabsf(__uint_as_float(pb)) - fabsf(__uint_as_float(qb));
                ns += __uint_as_float(__float_as_uint(phi2_f(a)) ^
                                      ((qb ^ pb) & 0x80000000u));
            }
        }
        orow[i * 1024 + tid] = -ns * LN2;   // leave scaled domain
    }
}

extern "C" void kernel_launch(void* const* d_in, const int* in_sizes, int n_in,
                              void* d_out, int out_size, void* d_ws, size_t ws_size,
                              hipStream_t stream) {
    const float* llr_ch = (const float*)d_in[0];
    const int* vn_con = (const int*)d_in[1];
    const int* cn_con = (const int*)d_in[2];
    int E = in_sizes[1];
    float* out = (float*)d_out;

    char* ws = (char*)d_ws;
    size_t off = 0;
    auto alloc = [&](size_t bytes) -> void* {
        void* ptr = ws + off;
        off = (off + bytes + 255) & ~(size_t)255;
        return ptr;
    };
    int* vn_ptr  = (int*)alloc((N_VNS + 1) * 4);
    int* cn_ptr  = (int*)alloc((N_CNS + 1) * 4);
    int* vn_cnt  = (int*)alloc(N_VNS * 4);
    int* cn_cnt  = (int*)alloc(N_CNS * 4);
    int* vn_fill = (int*)alloc(N_VNS * 4);
    int* vn_eids = (int*)alloc((size_t)E * 4);
    uint2* vn_pack = (uint2*)alloc((size_t)N_VNS * 8);

    hipMemsetAsync(vn_cnt, 0, N_VNS * 4, stream);
    hipMemsetAsync(cn_cnt, 0, N_CNS * 4, stream);
    hipMemsetAsync(vn_fill, 0, N_VNS * 4, stream);

    count_edges<<<(E + 255) / 256, 256, 0, stream>>>(vn_con, cn_con, E, vn_cnt, cn_cnt);
    scan_excl<<<1, 1024, 0, stream>>>(vn_cnt, N_VNS, vn_ptr);
    scan_excl<<<1, 1024, 0, stream>>>(cn_cnt, N_CNS, cn_ptr);
    fill_vn<<<(E + 255) / 256, 256, 0, stream>>>(vn_con, E, vn_ptr, vn_fill, vn_eids);
    sort_pack_vn<<<(N_VNS + 255) / 256, 256, 0, stream>>>(vn_ptr, vn_eids, cn_con, cn_ptr,
                                                          vn_pack);

    static bool attr_set = false;
    if (!attr_set) {
        hipFuncSetAttribute((const void*)decode,
                            hipFuncAttributeMaxDynamicSharedMemorySize, LDS_BYTES);
        attr_set = true;
    }
    decode<<<BATCH, 1024, LDS_BYTES, stream>>>(llr_ch, out, vn_pack);
}

// Round 8
// 465.667 us; speedup vs baseline: 1.2443x; 1.1645x over previous
//
#include <hip/hip_runtime.h>

#define N_VNS   8192
#define N_CNS   4096
#define BATCH   1024
#define NUM_ITER 20
#define MAX_E   24576           // == 6 * N_CNS, fixed 6-slot-per-CN SoA layout
#define LOG2E   1.44269504088896f
#define LN2     0.693147180559945f
#define YMAX2   24.0f           // PHI_MAX * log2e (ref clip upper bound)
// r-clamp (2^24-1)/(2^24+1): caps m at 24.0  == reference PHI_MIN input clip
#define RCLAMP  0x1.fffffcp-1f
// T-clamp 1-2^-24 == tanh of the PHI_MAX clip; also keeps products < 1.0
#define TCLAMP  0x1.fffffep-1f
#define LDS_BYTES (MAX_E * 4)

// t (log2-scaled LLR) -> T = tanh(t*ln2/2) = (2^t - 1)/(2^t + 1), signed.
__device__ __forceinline__ float t2T(float t) {
    float tc = fminf(fmaxf(t, -YMAX2), YMAX2);              // v_med3_f32
    float E = __builtin_amdgcn_exp2f(tc);
    float T = (E - 1.0f) * __builtin_amdgcn_rcpf(E + 1.0f);
    return fminf(fmaxf(T, -TCLAMP), TCLAMP);                // v_med3_f32
}

// exclusion product r -> message m = log2((1+r)/(1-r))  (signed, = 2atanh(r)*log2e)
__device__ __forceinline__ float r2m(float r) {
    float rc = fminf(fmaxf(r, -RCLAMP), RCLAMP);            // v_med3_f32
    return __builtin_amdgcn_logf((1.0f + rc) * __builtin_amdgcn_rcpf(1.0f - rc));
}

// ---------- setup kernels (run once per launch, ~10 us total) ----------

__global__ void count_edges(const int* __restrict__ vn_con, const int* __restrict__ cn_con,
                            int E, int* __restrict__ vn_cnt, int* __restrict__ cn_cnt) {
    int e = blockIdx.x * 256 + threadIdx.x;
    if (e < E) {
        atomicAdd(&vn_cnt[vn_con[e]], 1);
        atomicAdd(&cn_cnt[cn_con[e]], 1);
    }
}

__global__ void scan_excl(const int* __restrict__ cnt, int n, int* __restrict__ ptr) {
    __shared__ int sh[1024];
    int carry = 0;
    if (threadIdx.x == 0) ptr[0] = 0;
    for (int base = 0; base < n; base += 1024) {
        int i = base + (int)threadIdx.x;
        int v = (i < n) ? cnt[i] : 0;
        sh[threadIdx.x] = v;
        __syncthreads();
        for (int off = 1; off < 1024; off <<= 1) {
            int add = ((int)threadIdx.x >= off) ? sh[threadIdx.x - off] : 0;
            __syncthreads();
            sh[threadIdx.x] += add;
            __syncthreads();
        }
        if (i < n) ptr[i + 1] = carry + sh[threadIdx.x];
        carry += sh[1023];
        __syncthreads();
    }
}

__global__ void fill_vn(const int* __restrict__ vn_con, int E,
                        const int* __restrict__ vn_ptr, int* __restrict__ vn_fill,
                        int* __restrict__ vn_eids) {
    int e = blockIdx.x * 256 + threadIdx.x;
    if (e < E) {
        int v = vn_con[e];
        int slot = atomicAdd(&vn_fill[v], 1);
        vn_eids[vn_ptr[v] + slot] = e;
    }
}

// deterministic CSR: sort each vn's (<=3) edge ids ascending; pack three
// 16-bit SoA slots (slot = rank*N_CNS + cn < 24576, rank = eid - cn_ptr[cn])
// into a uint2. Sentinel 0xFFFF past degree. High half of .y reserved for a
// pad-restore slot (filled by pad_assign).
__global__ void sort_pack_vn(const int* __restrict__ vn_ptr, int* __restrict__ vn_eids,
                             const int* __restrict__ cn_con, const int* __restrict__ cn_ptr,
                             uint2* __restrict__ vn_pack) {
    int v = blockIdx.x * 256 + threadIdx.x;
    if (v >= N_VNS) return;
    int s = vn_ptr[v], n = vn_ptr[v + 1] - s;
    for (int i = 1; i < n; ++i) {
        int key = vn_eids[s + i];
        int j = i - 1;
        while (j >= 0 && vn_eids[s + j] > key) { vn_eids[s + j + 1] = vn_eids[s + j]; --j; }
        vn_eids[s + j + 1] = key;
    }
    unsigned sl[3];
    for (int k = 0; k < 3; ++k) {
        sl[k] = 0xFFFFu;
        if (k < n) {
            int eid = vn_eids[s + k];
            int cn = cn_con[eid];
            unsigned rank = (unsigned)(eid - cn_ptr[cn]);
            sl[k] = rank * N_CNS + (unsigned)cn;
        }
    }
    vn_pack[v] = make_uint2(sl[0] | (sl[1] << 16), sl[2] | 0xFFFF0000u);
}

// assign pad slots (rank >= deg) to volunteer threads: pad idx i is stored in
// vn_pack[i].y's high half (thread i%1024 reads it as pw[i/1024], i < 2048).
// Deterministic output: the SET of pads is fixed; restores are idempotent 1.0f.
__global__ void pad_assign(const int* __restrict__ cn_ptr, int* __restrict__ pad_cnt,
                           uint2* __restrict__ vn_pack) {
    int c = blockIdx.x * 256 + threadIdx.x;
    if (c >= N_CNS) return;
    int deg = cn_ptr[c + 1] - cn_ptr[c];
    for (int r = deg; r < 6; ++r) {
        int idx = atomicAdd(pad_cnt, 1);
        if (idx < 2048) {
            unsigned slot = (unsigned)r * N_CNS + (unsigned)c;
            vn_pack[idx].y = (vn_pack[idx].y & 0xFFFFu) | (slot << 16);
        }
    }
}

// ---------- the whole decode: one block per batch element ----------
// LDS: q[6][N_CNS] holds, alternately:
//   after VN phase: T_e = sgn(t_e)*tanh(|t_e|*ln2/2)   (pad slots = 1.0)
//   after CN phase: excl_e = prod_{k in cn(e), k!=e} T_k  (signed)
// CN phase: 6 stride-1 reads, 12 muls (prefix/suffix exclusion), 6 stride-1
// writes -- branchless, zero transcendentals, signs ride in the floats.
// VN phase: m = log2((1+r)/(1-r)) and T_new per edge: 4 transcendentals/edge.

__global__ __launch_bounds__(1024)
__attribute__((amdgpu_waves_per_eu(4, 4)))
void decode(const float* __restrict__ llr_ch, float* __restrict__ out,
            const uint2* __restrict__ vn_pack) {
    extern __shared__ float q[];        // [6][N_CNS]

    int b = blockIdx.x, tid = threadIdx.x;
    const float* llr_row = llr_ch + (size_t)b * N_VNS;

    float llr[8];
    uint2 pw[8];
    #pragma unroll
    for (int i = 0; i < 8; ++i) {
        int v = i * 1024 + tid;
        llr[i] = -llr_row[v] * LOG2E;   // enter log2-scaled domain
        pw[i] = vn_pack[v];
    }
    unsigned pad0 = pw[0].y >> 16;      // pad slots this thread restores
    unsigned pad1 = pw[1].y >> 16;

    // init all slots to the multiplicative identity, then own T0 = t2T(llr)
    #pragma unroll
    for (int k = 0; k < 24; ++k) q[k * 1024 + tid] = 1.0f;
    __syncthreads();
    #pragma unroll
    for (int i = 0; i < 8; ++i) {
        float T0 = t2T(llr[i]);
        unsigned s0 = pw[i].x & 0xFFFFu, s1 = pw[i].x >> 16, s2 = pw[i].y & 0xFFFFu;
        if (s0 != 0xFFFFu) q[s0] = T0;
        if (s1 != 0xFFFFu) q[s1] = T0;
        if (s2 != 0xFFFFu) q[s2] = T0;
    }
    __syncthreads();

    for (int it = 0; it < NUM_ITER; ++it) {
        // ---- CN phase: per-edge exclusion products via prefix/suffix ----
        #pragma unroll
        for (int i = 0; i < 4; ++i) {
            int c = i * 1024 + tid;
            float T0 = q[c];
            float T1 = q[N_CNS + c];
            float T2 = q[2 * N_CNS + c];
            float T3 = q[3 * N_CNS + c];
            float T4 = q[4 * N_CNS + c];
            float T5 = q[5 * N_CNS + c];
            float p1 = T0 * T1, p2 = p1 * T2, p3 = p2 * T3, p4 = p3 * T4;
            float s4 = T5 * T4, s3 = s4 * T3, s2 = s3 * T2, s1 = s2 * T1;
            q[c]             = s1;        // excl0
            q[N_CNS + c]     = T0 * s2;   // excl1
            q[2 * N_CNS + c] = p1 * s3;   // excl2
            q[3 * N_CNS + c] = p2 * s4;   // excl3
            q[4 * N_CNS + c] = p3 * T5;   // excl4
            q[5 * N_CNS + c] = p4;        // excl5
        }
        __syncthreads();
        if (it == NUM_ITER - 1) break;

        // ---- VN phase: msgs from excl, write T_new; restore pads ----
        #pragma unroll
        for (int i = 0; i < 8; ++i) {
            unsigned s0 = pw[i].x & 0xFFFFu, s1 = pw[i].x >> 16, s2 = pw[i].y & 0xFFFFu;
            float ns = llr[i];
            float m0 = 0.f, m1 = 0.f, m2 = 0.f;
            if (s0 != 0xFFFFu) { m0 = r2m(q[s0]); ns += m0; }
            if (s1 != 0xFFFFu) { m1 = r2m(q[s1]); ns += m1; }
            if (s2 != 0xFFFFu) { m2 = r2m(q[s2]); ns += m2; }
            if (s0 != 0xFFFFu) q[s0] = t2T(ns - m0);
            if (s1 != 0xFFFFu) q[s1] = t2T(ns - m1);
            if (s2 != 0xFFFFu) q[s2] = t2T(ns - m2);
        }
        if (pad0 != 0xFFFFu) q[pad0] = 1.0f;
        if (pad1 != 0xFFFFu) q[pad1] = 1.0f;
        __syncthreads();
    }

    // ---- marginalization: out[b][v] = -(llr + sum_e m_e) * ln2 ----
    float* orow = out + (size_t)b * N_VNS;
    #pragma unroll
    for (int i = 0; i < 8; ++i) {
        unsigned s0 = pw[i].x & 0xFFFFu, s1 = pw[i].x >> 16, s2 = pw[i].y & 0xFFFFu;
        float ns = llr[i];
        if (s0 != 0xFFFFu) ns += r2m(q[s0]);
        if (s1 != 0xFFFFu) ns += r2m(q[s1]);
        if (s2 != 0xFFFFu) ns += r2m(q[s2]);
        orow[i * 1024 + tid] = -ns * LN2;   // leave scaled domain
    }
}

extern "C" void kernel_launch(void* const* d_in, const int* in_sizes, int n_in,
                              void* d_out, int out_size, void* d_ws, size_t ws_size,
                              hipStream_t stream) {
    const float* llr_ch = (const float*)d_in[0];
    const int* vn_con = (const int*)d_in[1];
    const int* cn_con = (const int*)d_in[2];
    int E = in_sizes[1];
    float* out = (float*)d_out;

    char* ws = (char*)d_ws;
    size_t off = 0;
    auto alloc = [&](size_t bytes) -> void* {
        void* ptr = ws + off;
        off = (off + bytes + 255) & ~(size_t)255;
        return ptr;
    };
    int* vn_ptr  = (int*)alloc((N_VNS + 1) * 4);
    int* cn_ptr  = (int*)alloc((N_CNS + 1) * 4);
    int* vn_cnt  = (int*)alloc(N_VNS * 4);
    int* cn_cnt  = (int*)alloc(N_CNS * 4);
    int* vn_fill = (int*)alloc(N_VNS * 4);
    int* vn_eids = (int*)alloc((size_t)E * 4);
    uint2* vn_pack = (uint2*)alloc((size_t)N_VNS * 8);
    int* pad_cnt = (int*)alloc(4);

    hipMemsetAsync(vn_cnt, 0, N_VNS * 4, stream);
    hipMemsetAsync(cn_cnt, 0, N_CNS * 4, stream);
    hipMemsetAsync(vn_fill, 0, N_VNS * 4, stream);
    hipMemsetAsync(pad_cnt, 0, 4, stream);

    count_edges<<<(E + 255) / 256, 256, 0, stream>>>(vn_con, cn_con, E, vn_cnt, cn_cnt);
    scan_excl<<<1, 1024, 0, stream>>>(vn_cnt, N_VNS, vn_ptr);
    scan_excl<<<1, 1024, 0, stream>>>(cn_cnt, N_CNS, cn_ptr);
    fill_vn<<<(E + 255) / 256, 256, 0, stream>>>(vn_con, E, vn_ptr, vn_fill, vn_eids);
    sort_pack_vn<<<(N_VNS + 255) / 256, 256, 0, stream>>>(vn_ptr, vn_eids, cn_con, cn_ptr,
                                                          vn_pack);
    pad_assign<<<(N_CNS + 255) / 256, 256, 0, stream>>>(cn_ptr, pad_cnt, vn_pack);

    static bool attr_set = false;
    if (!attr_set) {
        hipFuncSetAttribute((const void*)decode,
                            hipFuncAttributeMaxDynamicSharedMemorySize, LDS_BYTES);
        attr_set = true;
    }
    decode<<<BATCH, 1024, LDS_BYTES, stream>>>(llr_ch, out, vn_pack);
}

// Round 9
// 352.084 us; speedup vs baseline: 1.6457x; 1.3226x over previous
//
#include <hip/hip_runtime.h>

#define N_VNS   8192
#define N_CNS   4096
#define BATCH   1024
#define NUM_ITER 20
#define MAX_E   24576           // == 6 * N_CNS, fixed 6-slot-per-CN SoA layout
#define LOG2E   1.44269504088896f
#define LN2     0.693147180559945f
#define YMAX2   24.0f           // PHI_MAX * log2e (ref clip upper bound)
// (2^24-1)/(2^24+1): tanh-domain image of BOTH reference clips --
//  read side: m <= 16.6355 (PHI_MIN clip); write side: |t| <= 16.6355 (PHI_MAX clip)
#define RCLAMP  0x1.fffffcp-1f
#define LDS_BYTES (MAX_E * 4)

// t (log2-scaled LLR) -> T = tanh(t*ln2/2) = (2^t - 1)/(2^t + 1), signed.
__device__ __forceinline__ float t2T(float t) {
    float tc = fminf(fmaxf(t, -YMAX2), YMAX2);              // v_med3_f32
    float E = __builtin_amdgcn_exp2f(tc);
    float T = (E - 1.0f) * __builtin_amdgcn_rcpf(E + 1.0f);
    return fminf(fmaxf(T, -RCLAMP), RCLAMP);                // v_med3_f32
}

// exclusion product r -> message m = log2((1+r)/(1-r)) (= 2atanh(r)*log2e)
__device__ __forceinline__ float r2m(float r) {
    float rc = fminf(fmaxf(r, -RCLAMP), RCLAMP);            // v_med3_f32
    return __builtin_amdgcn_logf((1.0f + rc) * __builtin_amdgcn_rcpf(1.0f - rc));
}

// ---------- setup kernels (run once per launch, ~10 us total) ----------

__global__ void count_edges(const int* __restrict__ vn_con, const int* __restrict__ cn_con,
                            int E, int* __restrict__ vn_cnt, int* __restrict__ cn_cnt) {
    int e = blockIdx.x * 256 + threadIdx.x;
    if (e < E) {
        atomicAdd(&vn_cnt[vn_con[e]], 1);
        atomicAdd(&cn_cnt[cn_con[e]], 1);
    }
}

__global__ void scan_excl(const int* __restrict__ cnt, int n, int* __restrict__ ptr) {
    __shared__ int sh[1024];
    int carry = 0;
    if (threadIdx.x == 0) ptr[0] = 0;
    for (int base = 0; base < n; base += 1024) {
        int i = base + (int)threadIdx.x;
        int v = (i < n) ? cnt[i] : 0;
        sh[threadIdx.x] = v;
        __syncthreads();
        for (int off = 1; off < 1024; off <<= 1) {
            int add = ((int)threadIdx.x >= off) ? sh[threadIdx.x - off] : 0;
            __syncthreads();
            sh[threadIdx.x] += add;
            __syncthreads();
        }
        if (i < n) ptr[i + 1] = carry + sh[threadIdx.x];
        carry += sh[1023];
        __syncthreads();
    }
}

__global__ void fill_vn(const int* __restrict__ vn_con, int E,
                        const int* __restrict__ vn_ptr, int* __restrict__ vn_fill,
                        int* __restrict__ vn_eids) {
    int e = blockIdx.x * 256 + threadIdx.x;
    if (e < E) {
        int v = vn_con[e];
        int slot = atomicAdd(&vn_fill[v], 1);
        vn_eids[vn_ptr[v] + slot] = e;
    }
}

// deterministic CSR: sort each vn's (<=3) edge ids ascending; pack three
// 16-bit SoA slots (slot = rank*N_CNS + cn < 24576, rank = eid - cn_ptr[cn])
// into a uint2. Sentinel 0xFFFF past degree. High half of .y reserved for a
// pad-restore slot (filled by pad_assign).
__global__ void sort_pack_vn(const int* __restrict__ vn_ptr, int* __restrict__ vn_eids,
                             const int* __restrict__ cn_con, const int* __restrict__ cn_ptr,
                             uint2* __restrict__ vn_pack) {
    int v = blockIdx.x * 256 + threadIdx.x;
    if (v >= N_VNS) return;
    int s = vn_ptr[v], n = vn_ptr[v + 1] - s;
    for (int i = 1; i < n; ++i) {
        int key = vn_eids[s + i];
        int j = i - 1;
        while (j >= 0 && vn_eids[s + j] > key) { vn_eids[s + j + 1] = vn_eids[s + j]; --j; }
        vn_eids[s + j + 1] = key;
    }
    unsigned sl[3];
    for (int k = 0; k < 3; ++k) {
        sl[k] = 0xFFFFu;
        if (k < n) {
            int eid = vn_eids[s + k];
            int cn = cn_con[eid];
            unsigned rank = (unsigned)(eid - cn_ptr[cn]);
            sl[k] = rank * N_CNS + (unsigned)cn;
        }
    }
    vn_pack[v] = make_uint2(sl[0] | (sl[1] << 16), sl[2] | 0xFFFF0000u);
}

// assign pad slots (rank >= deg) to volunteer threads: pad idx i is stored in
// vn_pack[i].y's high half (thread i%1024 reads it as pw[i/1024], i < 2048).
__global__ void pad_assign(const int* __restrict__ cn_ptr, int* __restrict__ pad_cnt,
                           uint2* __restrict__ vn_pack) {
    int c = blockIdx.x * 256 + threadIdx.x;
    if (c >= N_CNS) return;
    int deg = cn_ptr[c + 1] - cn_ptr[c];
    for (int r = deg; r < 6; ++r) {
        int idx = atomicAdd(pad_cnt, 1);
        if (idx < 2048) {
            unsigned slot = (unsigned)r * N_CNS + (unsigned)c;
            vn_pack[idx].y = (vn_pack[idx].y & 0xFFFFu) | (slot << 16);
        }
    }
}

// ---------- the whole decode: one block per batch element ----------
// LDS: q[6][N_CNS] holds, alternately:
//   after VN phase: T_e = tanh(t_e_nat/2), clamped +/-RCLAMP (pads = 1.0)
//   after CN phase: excl_e = prod_{k in cn(e), k!=e} T_k  (signed)
// CN phase: stride-1, 12 muls/CN, zero transcendentals.
// VN phase: pure tanh-domain message combining -- per VN: 3 pair (A,B) +
//   3 rational combines (T*A+B)*rcp(A+T*B). fma single-rounding makes the
//   1+ab cancellation exact; 3 rcp/VN total. No log/exp in the loop at all.
// Log domain only at entry (t2T) and exit (r2m): clips map exactly.

__global__ __launch_bounds__(1024)
__attribute__((amdgpu_waves_per_eu(4, 4)))
void decode(const float* __restrict__ llr_ch, float* __restrict__ out,
            const uint2* __restrict__ vn_pack) {
    extern __shared__ float q[];        // [6][N_CNS]

    int b = blockIdx.x, tid = threadIdx.x;
    const float* llr_row = llr_ch + (size_t)b * N_VNS;

    float llr[8];
    float Tllr[8];                      // tanh(llr_nat/2), loop-invariant
    uint2 pw[8];
    #pragma unroll
    for (int i = 0; i < 8; ++i) {
        int v = i * 1024 + tid;
        llr[i] = -llr_row[v] * LOG2E;   // enter log2-scaled domain
        pw[i] = vn_pack[v];
    }
    unsigned pad0 = pw[0].y >> 16;      // pad slots this thread restores
    unsigned pad1 = pw[1].y >> 16;

    // init all slots to the multiplicative identity, then own T0 = t2T(llr)
    #pragma unroll
    for (int k = 0; k < 24; ++k) q[k * 1024 + tid] = 1.0f;
    __syncthreads();
    #pragma unroll
    for (int i = 0; i < 8; ++i) {
        float T0 = t2T(llr[i]);
        Tllr[i] = T0;
        unsigned s0 = pw[i].x & 0xFFFFu, s1 = pw[i].x >> 16, s2 = pw[i].y & 0xFFFFu;
        if (s0 != 0xFFFFu) q[s0] = T0;
        if (s1 != 0xFFFFu) q[s1] = T0;
        if (s2 != 0xFFFFu) q[s2] = T0;
    }
    __syncthreads();

    for (int it = 0; it < NUM_ITER; ++it) {
        // ---- CN phase: per-edge exclusion products via prefix/suffix ----
        #pragma unroll
        for (int i = 0; i < 4; ++i) {
            int c = i * 1024 + tid;
            float T0 = q[c];
            float T1 = q[N_CNS + c];
            float T2 = q[2 * N_CNS + c];
            float T3 = q[3 * N_CNS + c];
            float T4 = q[4 * N_CNS + c];
            float T5 = q[5 * N_CNS + c];
            float p1 = T0 * T1, p2 = p1 * T2, p3 = p2 * T3, p4 = p3 * T4;
            float s4 = T5 * T4, s3 = s4 * T3, s2 = s3 * T2, s1 = s2 * T1;
            q[c]             = s1;        // excl0
            q[N_CNS + c]     = T0 * s2;   // excl1
            q[2 * N_CNS + c] = p1 * s3;   // excl2
            q[3 * N_CNS + c] = p2 * s4;   // excl3
            q[4 * N_CNS + c] = p3 * T5;   // excl4
            q[5 * N_CNS + c] = p4;        // excl5
        }
        __syncthreads();
        if (it == NUM_ITER - 1) break;

        // ---- VN phase: tanh-domain combine, no transcendentals ----
        #pragma unroll
        for (int i = 0; i < 8; ++i) {
            unsigned s0 = pw[i].x & 0xFFFFu, s1 = pw[i].x >> 16, s2 = pw[i].y & 0xFFFFu;
            // missing edges read as 0 (tanh-add identity)
            float r0 = 0.f, r1 = 0.f, r2 = 0.f;
            if (s0 != 0xFFFFu) r0 = fminf(fmaxf(q[s0], -RCLAMP), RCLAMP);
            if (s1 != 0xFFFFu) r1 = fminf(fmaxf(q[s1], -RCLAMP), RCLAMP);
            if (s2 != 0xFFFFu) r2 = fminf(fmaxf(q[s2], -RCLAMP), RCLAMP);
            float T = Tllr[i];
            // pair combines: A = 1 + rj*rl (fma: exact through cancellation), B = rj+rl
            float A12 = __builtin_fmaf(r1, r2, 1.0f), B12 = r1 + r2;
            float A02 = __builtin_fmaf(r0, r2, 1.0f), B02 = r0 + r2;
            float A01 = __builtin_fmaf(r0, r1, 1.0f), B01 = r0 + r1;
            // T_new_k = tanh_add(T, rj, rl) = (T*Ajl + Bjl) / (Ajl + T*Bjl)
            float n0 = __builtin_fmaf(T, A12, B12), d0 = __builtin_fmaf(T, B12, A12);
            float n1 = __builtin_fmaf(T, A02, B02), d1 = __builtin_fmaf(T, B02, A02);
            float n2 = __builtin_fmaf(T, A01, B01), d2 = __builtin_fmaf(T, B01, A01);
            float t0 = n0 * __builtin_amdgcn_rcpf(d0);
            float t1 = n1 * __builtin_amdgcn_rcpf(d1);
            float t2 = n2 * __builtin_amdgcn_rcpf(d2);
            t0 = fminf(fmaxf(t0, -RCLAMP), RCLAMP);
            t1 = fminf(fmaxf(t1, -RCLAMP), RCLAMP);
            t2 = fminf(fmaxf(t2, -RCLAMP), RCLAMP);
            if (s0 != 0xFFFFu) q[s0] = t0;
            if (s1 != 0xFFFFu) q[s1] = t1;
            if (s2 != 0xFFFFu) q[s2] = t2;
        }
        if (pad0 != 0xFFFFu) q[pad0] = 1.0f;
        if (pad1 != 0xFFFFu) q[pad1] = 1.0f;
        __syncthreads();
    }

    // ---- marginalization: out[b][v] = -(llr + sum_e m_e) * ln2 ----
    float* orow = out + (size_t)b * N_VNS;
    #pragma unroll
    for (int i = 0; i < 8; ++i) {
        unsigned s0 = pw[i].x & 0xFFFFu, s1 = pw[i].x >> 16, s2 = pw[i].y & 0xFFFFu;
        float ns = llr[i];
        if (s0 != 0xFFFFu) ns += r2m(q[s0]);
        if (s1 != 0xFFFFu) ns += r2m(q[s1]);
        if (s2 != 0xFFFFu) ns += r2m(q[s2]);
        orow[i * 1024 + tid] = -ns * LN2;   // leave scaled domain
    }
}

extern "C" void kernel_launch(void* const* d_in, const int* in_sizes, int n_in,
                              void* d_out, int out_size, void* d_ws, size_t ws_size,
                              hipStream_t stream) {
    const float* llr_ch = (const float*)d_in[0];
    const int* vn_con = (const int*)d_in[1];
    const int* cn_con = (const int*)d_in[2];
    int E = in_sizes[1];
    float* out = (float*)d_out;

    char* ws = (char*)d_ws;
    size_t off = 0;
    auto alloc = [&](size_t bytes) -> void* {
        void* ptr = ws + off;
        off = (off + bytes + 255) & ~(size_t)255;
        return ptr;
    };
    int* vn_ptr  = (int*)alloc((N_VNS + 1) * 4);
    int* cn_ptr  = (int*)alloc((N_CNS + 1) * 4);
    int* vn_cnt  = (int*)alloc(N_VNS * 4);
    int* cn_cnt  = (int*)alloc(N_CNS * 4);
    int* vn_fill = (int*)alloc(N_VNS * 4);
    int* vn_eids = (int*)alloc((size_t)E * 4);
    uint2* vn_pack = (uint2*)alloc((size_t)N_VNS * 8);
    int* pad_cnt = (int*)alloc(4);

    hipMemsetAsync(vn_cnt, 0, N_VNS * 4, stream);
    hipMemsetAsync(cn_cnt, 0, N_CNS * 4, stream);
    hipMemsetAsync(vn_fill, 0, N_VNS * 4, stream);
    hipMemsetAsync(pad_cnt, 0, 4, stream);

    count_edges<<<(E + 255) / 256, 256, 0, stream>>>(vn_con, cn_con, E, vn_cnt, cn_cnt);
    scan_excl<<<1, 1024, 0, stream>>>(vn_cnt, N_VNS, vn_ptr);
    scan_excl<<<1, 1024, 0, stream>>>(cn_cnt, N_CNS, cn_ptr);
    fill_vn<<<(E + 255) / 256, 256, 0, stream>>>(vn_con, E, vn_ptr, vn_fill, vn_eids);
    sort_pack_vn<<<(N_VNS + 255) / 256, 256, 0, stream>>>(vn_ptr, vn_eids, cn_con, cn_ptr,
                                                          vn_pack);
    pad_assign<<<(N_CNS + 255) / 256, 256, 0, stream>>>(cn_ptr, pad_cnt, vn_pack);

    static bool attr_set = false;
    if (!attr_set) {
        hipFuncSetAttribute((const void*)decode,
                            hipFuncAttributeMaxDynamicSharedMemorySize, LDS_BYTES);
        attr_set = true;
    }
    decode<<<BATCH, 1024, LDS_BYTES, stream>>>(llr_ch, out, vn_pack);
}

// Round 10
// 336.911 us; speedup vs baseline: 1.7199x; 1.0450x over previous
//
#include <hip/hip_runtime.h>

#define N_VNS   8192
#define N_CNS   4096
#define BATCH   1024
#define NUM_ITER 20
#define MAX_E   24576           // == 6 * N_CNS, rank-pair-interleaved layout
#define LOG2E   1.44269504088896f
#define LN2     0.693147180559945f
#define YMAX2   24.0f           // PHI_MAX * log2e (ref clip upper bound)
// (2^24-1)/(2^24+1): tanh-domain image of BOTH reference clips
#define RCLAMP  0x1.fffffcp-1f
#define ZSLOT   24576           // shared always-zero slot (tanh-add identity)
#define ZBYTE   (ZSLOT * 4)
#define LDS_BYTES ((MAX_E + 64) * 4)

typedef float v2f __attribute__((ext_vector_type(2)));

// t (log2-scaled LLR) -> T = tanh(t*ln2/2) = (2^t - 1)/(2^t + 1), signed.
__device__ __forceinline__ float t2T(float t) {
    float tc = fminf(fmaxf(t, -YMAX2), YMAX2);
    float E = __builtin_amdgcn_exp2f(tc);
    float T = (E - 1.0f) * __builtin_amdgcn_rcpf(E + 1.0f);
    return fminf(fmaxf(T, -RCLAMP), RCLAMP);
}

// exclusion product r -> message m = log2((1+r)/(1-r)) (= 2atanh(r)*log2e)
__device__ __forceinline__ float r2m(float r) {
    float rc = fminf(fmaxf(r, -RCLAMP), RCLAMP);
    return __builtin_amdgcn_logf((1.0f + rc) * __builtin_amdgcn_rcpf(1.0f - rc));
}

// interleaved SoA slot: ranks (2j, 2j+1) of cn c adjacent -> CN phase uses b64
__device__ __forceinline__ unsigned qslot(unsigned rank, unsigned cn) {
    return (rank >> 1) * (2 * N_CNS) + cn * 2 + (rank & 1);
}

// ---------- setup kernels (run once per launch, ~10 us total) ----------

__global__ void count_edges(const int* __restrict__ vn_con, const int* __restrict__ cn_con,
                            int E, int* __restrict__ vn_cnt, int* __restrict__ cn_cnt) {
    int e = blockIdx.x * 256 + threadIdx.x;
    if (e < E) {
        atomicAdd(&vn_cnt[vn_con[e]], 1);
        atomicAdd(&cn_cnt[cn_con[e]], 1);
    }
}

__global__ void scan_excl(const int* __restrict__ cnt, int n, int* __restrict__ ptr) {
    __shared__ int sh[1024];
    int carry = 0;
    if (threadIdx.x == 0) ptr[0] = 0;
    for (int base = 0; base < n; base += 1024) {
        int i = base + (int)threadIdx.x;
        int v = (i < n) ? cnt[i] : 0;
        sh[threadIdx.x] = v;
        __syncthreads();
        for (int off = 1; off < 1024; off <<= 1) {
            int add = ((int)threadIdx.x >= off) ? sh[threadIdx.x - off] : 0;
            __syncthreads();
            sh[threadIdx.x] += add;
            __syncthreads();
        }
        if (i < n) ptr[i + 1] = carry + sh[threadIdx.x];
        carry += sh[1023];
        __syncthreads();
    }
}

__global__ void fill_vn(const int* __restrict__ vn_con, int E,
                        const int* __restrict__ vn_ptr, int* __restrict__ vn_fill,
                        int* __restrict__ vn_eids) {
    int e = blockIdx.x * 256 + threadIdx.x;
    if (e < E) {
        int v = vn_con[e];
        int slot = atomicAdd(&vn_fill[v], 1);
        vn_eids[vn_ptr[v] + slot] = e;
    }
}

// deterministic CSR: sort each vn's (<=3) edge ids ascending; pack three
// 16-bit interleaved slots into a uint2 (sentinel 0xFFFF past degree).
// High half of .y: a pad-restore slot (filled by pad_assign).
__global__ void sort_pack_vn(const int* __restrict__ vn_ptr, int* __restrict__ vn_eids,
                             const int* __restrict__ cn_con, const int* __restrict__ cn_ptr,
                             uint2* __restrict__ vn_pack) {
    int v = blockIdx.x * 256 + threadIdx.x;
    if (v >= N_VNS) return;
    int s = vn_ptr[v], n = vn_ptr[v + 1] - s;
    for (int i = 1; i < n; ++i) {
        int key = vn_eids[s + i];
        int j = i - 1;
        while (j >= 0 && vn_eids[s + j] > key) { vn_eids[s + j + 1] = vn_eids[s + j]; --j; }
        vn_eids[s + j + 1] = key;
    }
    unsigned sl[3];
    for (int k = 0; k < 3; ++k) {
        sl[k] = 0xFFFFu;
        if (k < n) {
            int eid = vn_eids[s + k];
            int cn = cn_con[eid];
            unsigned rank = (unsigned)(eid - cn_ptr[cn]);
            sl[k] = qslot(rank, (unsigned)cn);
        }
    }
    vn_pack[v] = make_uint2(sl[0] | (sl[1] << 16), sl[2] | 0xFFFF0000u);
}

// assign pad slots (rank >= deg, stay 1.0) to volunteer threads via
// vn_pack[idx].y high half, idx < 2048 (actual pad count is tiny).
__global__ void pad_assign(const int* __restrict__ cn_ptr, int* __restrict__ pad_cnt,
                           uint2* __restrict__ vn_pack) {
    int c = blockIdx.x * 256 + threadIdx.x;
    if (c >= N_CNS) return;
    int deg = cn_ptr[c + 1] - cn_ptr[c];
    for (int r = deg; r < 6; ++r) {
        int idx = atomicAdd(pad_cnt, 1);
        if (idx < 2048) {
            unsigned slot = qslot((unsigned)r, (unsigned)c);
            vn_pack[idx].y = (vn_pack[idx].y & 0xFFFFu) | (slot << 16);
        }
    }
}

// ---------- the whole decode: one block per batch element ----------
// LDS q (rank-pair interleaved [3][N_CNS][2]) holds, alternately:
//   after VN phase: T_e = tanh(t_e_nat/2), clamped +/-RCLAMP (pads = 1.0)
//   after CN phase: excl_e = prod_{k in cn(e), k!=e} T_k  (signed)
// Slot ZSLOT is the branchless missing-edge target: reads give 0 (tanh-add
// identity); writes there are value-selected to 0, so it stays 0 forever.
// CN phase: 3x ds_read_b64 + 12 muls (float2/pk) + 3x ds_write_b64 per CN.
// VN phase: per VN 3 scattered reads (NO clamps -- |q| <= RCLAMP provably),
// 3 fma-pairs + 3 rational combines + 3 rcp, write-clamp, scattered writes.
// All byte addresses precomputed once in VGPRs.

__global__ __launch_bounds__(1024)
__attribute__((amdgpu_waves_per_eu(4, 4)))
void decode(const float* __restrict__ llr_ch, float* __restrict__ out,
            const uint2* __restrict__ vn_pack) {
    extern __shared__ float q[];
    char* qb = (char*)q;

    int b = blockIdx.x, tid = threadIdx.x;
    const float* llr_row = llr_ch + (size_t)b * N_VNS;

    float llr[8];                       // log2-scaled channel LLR
    float Tllr[8];                      // tanh(llr_nat/2), loop-invariant
    unsigned a[8][3];                   // byte addresses of own edge slots
    unsigned pad0, pad1;
    {
        uint2 pw0 = vn_pack[tid], pw1 = vn_pack[1024 + tid];
        pad0 = pw0.y >> 16;
        pad1 = pw1.y >> 16;
        #pragma unroll
        for (int i = 0; i < 8; ++i) {
            int v = i * 1024 + tid;
            uint2 pw = (i == 0) ? pw0 : (i == 1) ? pw1 : vn_pack[v];
            llr[i] = -llr_row[v] * LOG2E;
            Tllr[i] = t2T(llr[i]);
            unsigned s0 = pw.x & 0xFFFFu, s1 = pw.x >> 16, s2 = pw.y & 0xFFFFu;
            a[i][0] = (s0 == 0xFFFFu) ? ZBYTE : s0 * 4;
            a[i][1] = (s1 == 0xFFFFu) ? ZBYTE : s1 * 4;
            a[i][2] = (s2 == 0xFFFFu) ? ZBYTE : s2 * 4;
        }
        pad0 = (pad0 == 0xFFFFu) ? 0xFFFFFFFFu : pad0 * 4;
        pad1 = (pad1 == 0xFFFFu) ? 0xFFFFFFFFu : pad1 * 4;
    }

    // init: all slots 1.0 (covers pads), Z slot 0, then own T0 (0 if missing)
    #pragma unroll
    for (int k = 0; k < 24; ++k) q[k * 1024 + tid] = 1.0f;
    if (tid == 0) q[ZSLOT] = 0.0f;
    __syncthreads();
    #pragma unroll
    for (int i = 0; i < 8; ++i) {
        float T0 = Tllr[i];
        #pragma unroll
        for (int k = 0; k < 3; ++k)
            *(float*)(qb + a[i][k]) = (a[i][k] == ZBYTE) ? 0.0f : T0;
    }
    __syncthreads();

    for (int it = 0; it < NUM_ITER; ++it) {
        // ---- CN phase: per-edge exclusion products via prefix/suffix ----
        #pragma unroll
        for (int i = 0; i < 4; ++i) {
            unsigned c8 = (unsigned)(i * 1024 + tid) * 8u;
            v2f T01 = *(v2f*)(qb + c8);
            v2f T23 = *(v2f*)(qb + 32768 + c8);
            v2f T45 = *(v2f*)(qb + 65536 + c8);
            float T0 = T01.x, T1 = T01.y, T2 = T23.x, T3 = T23.y, T4 = T45.x, T5 = T45.y;
            float p1 = T0 * T1, p2 = p1 * T2, p3 = p2 * T3, p4 = p3 * T4;
            float s4 = T5 * T4, s3 = s4 * T3, s2 = s3 * T2, s1 = s2 * T1;
            v2f e01 = { s1, T0 * s2 };
            v2f e23 = { p1 * s3, p2 * s4 };
            v2f e45 = { p3 * T5, p4 };
            *(v2f*)(qb + c8) = e01;
            *(v2f*)(qb + 32768 + c8) = e23;
            *(v2f*)(qb + 65536 + c8) = e45;
        }
        __syncthreads();
        if (it == NUM_ITER - 1) break;

        // ---- VN phase: tanh-domain combine, branchless ----
        #pragma unroll
        for (int i = 0; i < 8; ++i) {
            float r0 = *(float*)(qb + a[i][0]);   // |r| <= RCLAMP by construction
            float r1 = *(float*)(qb + a[i][1]);
            float r2 = *(float*)(qb + a[i][2]);
            float T = Tllr[i];
            float A12 = __builtin_fmaf(r1, r2, 1.0f), B12 = r1 + r2;
            float A02 = __builtin_fmaf(r0, r2, 1.0f), B02 = r0 + r2;
            float A01 = __builtin_fmaf(r0, r1, 1.0f), B01 = r0 + r1;
            float n0 = __builtin_fmaf(T, A12, B12), d0 = __builtin_fmaf(T, B12, A12);
            float n1 = __builtin_fmaf(T, A02, B02), d1 = __builtin_fmaf(T, B02, A02);
            float n2 = __builtin_fmaf(T, A01, B01), d2 = __builtin_fmaf(T, B01, A01);
            float t0 = n0 * __builtin_amdgcn_rcpf(d0);
            float t1 = n1 * __builtin_amdgcn_rcpf(d1);
            float t2 = n2 * __builtin_amdgcn_rcpf(d2);
            t0 = fminf(fmaxf(t0, -RCLAMP), RCLAMP);
            t1 = fminf(fmaxf(t1, -RCLAMP), RCLAMP);
            t2 = fminf(fmaxf(t2, -RCLAMP), RCLAMP);
            // keep Z slot zero: missing-edge writes select 0
            *(float*)(qb + a[i][0]) = (a[i][0] == ZBYTE) ? 0.0f : t0;
            *(float*)(qb + a[i][1]) = (a[i][1] == ZBYTE) ? 0.0f : t1;
            *(float*)(qb + a[i][2]) = (a[i][2] == ZBYTE) ? 0.0f : t2;
        }
        if (pad0 != 0xFFFFFFFFu) *(float*)(qb + pad0) = 1.0f;
        if (pad1 != 0xFFFFFFFFu) *(float*)(qb + pad1) = 1.0f;
        __syncthreads();
    }

    // ---- marginalization: out[b][v] = -(llr + sum_e m_e) * ln2 ----
    float* orow = out + (size_t)b * N_VNS;
    #pragma unroll
    for (int i = 0; i < 8; ++i) {
        float ns = llr[i];
        ns += r2m(*(float*)(qb + a[i][0]));   // r2m(0) = 0 for missing edges
        ns += r2m(*(float*)(qb + a[i][1]));
        ns += r2m(*(float*)(qb + a[i][2]));
        orow[i * 1024 + tid] = -ns * LN2;
    }
}

extern "C" void kernel_launch(void* const* d_in, const int* in_sizes, int n_in,
                              void* d_out, int out_size, void* d_ws, size_t ws_size,
                              hipStream_t stream) {
    const float* llr_ch = (const float*)d_in[0];
    const int* vn_con = (const int*)d_in[1];
    const int* cn_con = (const int*)d_in[2];
    int E = in_sizes[1];
    float* out = (float*)d_out;

    char* ws = (char*)d_ws;
    size_t off = 0;
    auto alloc = [&](size_t bytes) -> void* {
        void* ptr = ws + off;
        off = (off + bytes + 255) & ~(size_t)255;
        return ptr;
    };
    int* vn_ptr  = (int*)alloc((N_VNS + 1) * 4);
    int* cn_ptr  = (int*)alloc((N_CNS + 1) * 4);
    int* vn_cnt  = (int*)alloc(N_VNS * 4);
    int* cn_cnt  = (int*)alloc(N_CNS * 4);
    int* vn_fill = (int*)alloc(N_VNS * 4);
    int* vn_eids = (int*)alloc((size_t)E * 4);
    uint2* vn_pack = (uint2*)alloc((size_t)N_VNS * 8);
    int* pad_cnt = (int*)alloc(4);

    hipMemsetAsync(vn_cnt, 0, N_VNS * 4, stream);
    hipMemsetAsync(cn_cnt, 0, N_CNS * 4, stream);
    hipMemsetAsync(vn_fill, 0, N_VNS * 4, stream);
    hipMemsetAsync(pad_cnt, 0, 4, stream);

    count_edges<<<(E + 255) / 256, 256, 0, stream>>>(vn_con, cn_con, E, vn_cnt, cn_cnt);
    scan_excl<<<1, 1024, 0, stream>>>(vn_cnt, N_VNS, vn_ptr);
    scan_excl<<<1, 1024, 0, stream>>>(cn_cnt, N_CNS, cn_ptr);
    fill_vn<<<(E + 255) / 256, 256, 0, stream>>>(vn_con, E, vn_ptr, vn_fill, vn_eids);
    sort_pack_vn<<<(N_VNS + 255) / 256, 256, 0, stream>>>(vn_ptr, vn_eids, cn_con, cn_ptr,
                                                          vn_pack);
    pad_assign<<<(N_CNS + 255) / 256, 256, 0, stream>>>(cn_ptr, pad_cnt, vn_pack);

    static bool attr_set = false;
    if (!attr_set) {
        hipFuncSetAttribute((const void*)decode,
                            hipFuncAttributeMaxDynamicSharedMemorySize, LDS_BYTES);
        attr_set = true;
    }
    decode<<<BATCH, 1024, LDS_BYTES, stream>>>(llr_ch, out, vn_pack);
}

// Round 11
// 335.025 us; speedup vs baseline: 1.7295x; 1.0056x over previous
//
#include <hip/hip_runtime.h>

#define N_VNS   8192
#define N_CNS   4096
#define BATCH   1024
#define NUM_ITER 20
#define MAX_E   24576           // == 6 * N_CNS
#define LOG2E   1.44269504088896f
#define LN2     0.693147180559945f
// (2^24-1)/(2^24+1): tanh-domain image of the reference PHI_MAX clip
#define RCLAMP  0x1.fffffcp-1f
// tanh(PHI_MIN/2): tanh-domain image of the reference PHI_MIN clip; also
// keeps rcp(T) finite (never divide by 0)
#define TMIN    4.25e-08f
// LDS word map: T quad-interleaved [0,24576) + scratch 24576; P at PBASE
#define TSCRATCH 24576
#define PBASE    24640
#define PZERO    (PBASE + N_CNS)
#define LDS_WORDS (PZERO + 64)
#define LDS_BYTES (LDS_WORDS * 4)

typedef float v2f __attribute__((ext_vector_type(2)));
typedef float v4f __attribute__((ext_vector_type(4)));

// t (log2-scaled LLR) -> T = tanh(t*ln2/2) = (2^t - 1)/(2^t + 1), signed.
__device__ __forceinline__ float t2T(float t) {
    float tc = fminf(fmaxf(t, -24.0f), 24.0f);
    float E = __builtin_amdgcn_exp2f(tc);
    return (E - 1.0f) * __builtin_amdgcn_rcpf(E + 1.0f);
}

// message value r -> m = log2((1+r)/(1-r)) (= 2atanh(r)*log2e)
__device__ __forceinline__ float r2m(float r) {
    float rc = fminf(fmaxf(r, -RCLAMP), RCLAMP);
    return __builtin_amdgcn_logf((1.0f + rc) * __builtin_amdgcn_rcpf(1.0f - rc));
}

// write guard == BOTH reference clips in tanh domain: TMIN <= |T| <= RCLAMP
__device__ __forceinline__ float guardT(float t) {
    float m = fminf(fmaxf(fabsf(t), TMIN), RCLAMP);
    return __builtin_copysignf(m, t);
}

// ---------- setup kernels (run once per launch, ~10 us total) ----------

__global__ void count_edges(const int* __restrict__ vn_con, const int* __restrict__ cn_con,
                            int E, int* __restrict__ vn_cnt, int* __restrict__ cn_cnt) {
    int e = blockIdx.x * 256 + threadIdx.x;
    if (e < E) {
        atomicAdd(&vn_cnt[vn_con[e]], 1);
        atomicAdd(&cn_cnt[cn_con[e]], 1);
    }
}

__global__ void scan_excl(const int* __restrict__ cnt, int n, int* __restrict__ ptr) {
    __shared__ int sh[1024];
    int carry = 0;
    if (threadIdx.x == 0) ptr[0] = 0;
    for (int base = 0; base < n; base += 1024) {
        int i = base + (int)threadIdx.x;
        int v = (i < n) ? cnt[i] : 0;
        sh[threadIdx.x] = v;
        __syncthreads();
        for (int off = 1; off < 1024; off <<= 1) {
            int add = ((int)threadIdx.x >= off) ? sh[threadIdx.x - off] : 0;
            __syncthreads();
            sh[threadIdx.x] += add;
            __syncthreads();
        }
        if (i < n) ptr[i + 1] = carry + sh[threadIdx.x];
        carry += sh[1023];
        __syncthreads();
    }
}

__global__ void fill_vn(const int* __restrict__ vn_con, int E,
                        const int* __restrict__ vn_ptr, int* __restrict__ vn_fill,
                        int* __restrict__ vn_eids) {
    int e = blockIdx.x * 256 + threadIdx.x;
    if (e < E) {
        int v = vn_con[e];
        int slot = atomicAdd(&vn_fill[v], 1);
        vn_eids[vn_ptr[v] + slot] = e;
    }
}

// deterministic CSR: sort each vn's (<=3) edge ids ascending; pack three
// 16-bit T-slots into a uint2 (sentinel 0xFFFF past degree).
// Quad-interleaved T slot: rank<4: cn*4+rank; rank 4,5: 16384 + cn*2 + rank-4
// -> CN phase reads ranks 0-3 as one b128 and ranks 4-5 as one b64.
__global__ void sort_pack_vn(const int* __restrict__ vn_ptr, int* __restrict__ vn_eids,
                             const int* __restrict__ cn_con, const int* __restrict__ cn_ptr,
                             uint2* __restrict__ vn_pack) {
    int v = blockIdx.x * 256 + threadIdx.x;
    if (v >= N_VNS) return;
    int s = vn_ptr[v], n = vn_ptr[v + 1] - s;
    for (int i = 1; i < n; ++i) {
        int key = vn_eids[s + i];
        int j = i - 1;
        while (j >= 0 && vn_eids[s + j] > key) { vn_eids[s + j + 1] = vn_eids[s + j]; --j; }
        vn_eids[s + j + 1] = key;
    }
    unsigned sl[3];
    for (int k = 0; k < 3; ++k) {
        sl[k] = 0xFFFFu;
        if (k < n) {
            int eid = vn_eids[s + k];
            int cn = cn_con[eid];
            unsigned rank = (unsigned)(eid - cn_ptr[cn]);
            sl[k] = (rank < 4) ? ((unsigned)cn * 4 + rank)
                               : (16384u + (unsigned)cn * 2 + (rank - 4));
        }
    }
    vn_pack[v] = make_uint2(sl[0] | (sl[1] << 16), sl[2]);
}

// ---------- the whole decode: one block per batch element ----------
// LDS: T (quad-interleaved, 24576 + scratch): written ONLY by VN phase,
//        read ONLY by CN phase (b128+b64, conflict-free). Pad slots (deg<6)
//        stay 1.0 forever -- CN never writes T.
//      P[N_CNS] (+ zero slot): P_c = prod of all 6 T -- written by CN (1 b32,
//        contiguous), read scattered by VN.
// VN recovers excl_e = P * rcp(T_own_e) from its register copy qr (|P| <=
// |T_own| so |excl| <= 1+eps), combines in tanh domain (fma-exact), and
// writes guarded T_new. guardT == both reference clips; rcp args never 0.

__global__ __launch_bounds__(1024)
__attribute__((amdgpu_waves_per_eu(4, 4)))
void decode(const float* __restrict__ llr_ch, float* __restrict__ out,
            const uint2* __restrict__ vn_pack) {
    extern __shared__ float q[];
    char* qb = (char*)q;

    int b = blockIdx.x, tid = threadIdx.x;
    const float* llr_row = llr_ch + (size_t)b * N_VNS;

    float llr[8];                       // log2-scaled channel LLR
    float Tllr[8];                      // guarded tanh(llr_nat/2), loop-invariant
    float qr[8][3];                     // register copy of own T values
    unsigned aT[8][3];                  // byte addr of own T slots
    unsigned aP[8][3];                  // byte addr of own cn's P slot
    #pragma unroll
    for (int i = 0; i < 8; ++i) {
        int v = i * 1024 + tid;
        uint2 pw = vn_pack[v];
        llr[i] = -llr_row[v] * LOG2E;
        Tllr[i] = guardT(t2T(llr[i]));
        unsigned s[3] = { pw.x & 0xFFFFu, pw.x >> 16, pw.y & 0xFFFFu };
        #pragma unroll
        for (int k = 0; k < 3; ++k) {
            unsigned sk = s[k];
            bool miss = (sk == 0xFFFFu);
            unsigned cn = (sk < 16384u) ? (sk >> 2) : ((sk - 16384u) >> 1);
            aT[i][k] = miss ? (TSCRATCH * 4u) : (sk * 4u);
            aP[i][k] = miss ? (PZERO * 4u) : ((PBASE + cn) * 4u);
        }
    }

    // init: T region (incl. scratch + pads) = 1.0; P zero slot = 0
    #pragma unroll
    for (int k = 0; k < 24; ++k) q[k * 1024 + tid] = 1.0f;
    if (tid == 0) { q[TSCRATCH] = 1.0f; q[PZERO] = 0.0f; }
    __syncthreads();
    // initial T_e = tanh-image of channel LLR (missing edges -> scratch)
    #pragma unroll
    for (int i = 0; i < 8; ++i) {
        float T0 = Tllr[i];
        #pragma unroll
        for (int k = 0; k < 3; ++k) { qr[i][k] = T0; *(float*)(qb + aT[i][k]) = T0; }
    }
    __syncthreads();

    for (int it = 0; it < NUM_ITER; ++it) {
        // ---- CN phase: P_c = prod of 6 T (b128 + b64 reads, b32 write) ----
        #pragma unroll
        for (int i = 0; i < 4; ++i) {
            unsigned c = (unsigned)(i * 1024 + tid);
            v4f T03 = *(v4f*)(qb + c * 16u);
            v2f T45 = *(v2f*)(qb + 65536u + c * 8u);
            float P = ((((T03.x * T03.y) * T03.z) * T03.w) * T45.x) * T45.y;
            *(float*)(qb + (PBASE * 4u) + c * 4u) = P;
        }
        __syncthreads();
        if (it == NUM_ITER - 1) break;

        // ---- VN phase: excl by division, tanh-domain combine, write T ----
        #pragma unroll
        for (int i = 0; i < 8; ++i) {
            float P0 = *(float*)(qb + aP[i][0]);
            float P1 = *(float*)(qb + aP[i][1]);
            float P2 = *(float*)(qb + aP[i][2]);
            float r0 = P0 * __builtin_amdgcn_rcpf(qr[i][0]);
            float r1 = P1 * __builtin_amdgcn_rcpf(qr[i][1]);
            float r2 = P2 * __builtin_amdgcn_rcpf(qr[i][2]);
            float T = Tllr[i];
            float A12 = __builtin_fmaf(r1, r2, 1.0f), B12 = r1 + r2;
            float A02 = __builtin_fmaf(r0, r2, 1.0f), B02 = r0 + r2;
            float A01 = __builtin_fmaf(r0, r1, 1.0f), B01 = r0 + r1;
            float n0 = __builtin_fmaf(T, A12, B12), d0 = __builtin_fmaf(T, B12, A12);
            float n1 = __builtin_fmaf(T, A02, B02), d1 = __builtin_fmaf(T, B02, A02);
            float n2 = __builtin_fmaf(T, A01, B01), d2 = __builtin_fmaf(T, B01, A01);
            float t0 = guardT(n0 * __builtin_amdgcn_rcpf(d0));
            float t1 = guardT(n1 * __builtin_amdgcn_rcpf(d1));
            float t2 = guardT(n2 * __builtin_amdgcn_rcpf(d2));
            qr[i][0] = t0; *(float*)(qb + aT[i][0]) = t0;
            qr[i][1] = t1; *(float*)(qb + aT[i][1]) = t1;
            qr[i][2] = t2; *(float*)(qb + aT[i][2]) = t2;
        }
        __syncthreads();
    }

    // ---- marginalization: out[b][v] = -(llr + sum_e m_e) * ln2 ----
    float* orow = out + (size_t)b * N_VNS;
    #pragma unroll
    for (int i = 0; i < 8; ++i) {
        float ns = llr[i];
        ns += r2m(*(float*)(qb + aP[i][0]) * __builtin_amdgcn_rcpf(qr[i][0]));
        ns += r2m(*(float*)(qb + aP[i][1]) * __builtin_amdgcn_rcpf(qr[i][1]));
        ns += r2m(*(float*)(qb + aP[i][2]) * __builtin_amdgcn_rcpf(qr[i][2]));
        orow[i * 1024 + tid] = -ns * LN2;
    }
}

extern "C" void kernel_launch(void* const* d_in, const int* in_sizes, int n_in,
                              void* d_out, int out_size, void* d_ws, size_t ws_size,
                              hipStream_t stream) {
    const float* llr_ch = (const float*)d_in[0];
    const int* vn_con = (const int*)d_in[1];
    const int* cn_con = (const int*)d_in[2];
    int E = in_sizes[1];
    float* out = (float*)d_out;

    char* ws = (char*)d_ws;
    size_t off = 0;
    auto alloc = [&](size_t bytes) -> void* {
        void* ptr = ws + off;
        off = (off + bytes + 255) & ~(size_t)255;
        return ptr;
    };
    int* vn_ptr  = (int*)alloc((N_VNS + 1) * 4);
    int* cn_ptr  = (int*)alloc((N_CNS + 1) * 4);
    int* vn_cnt  = (int*)alloc(N_VNS * 4);
    int* cn_cnt  = (int*)alloc(N_CNS * 4);
    int* vn_fill = (int*)alloc(N_VNS * 4);
    int* vn_eids = (int*)alloc((size_t)E * 4);
    uint2* vn_pack = (uint2*)alloc((size_t)N_VNS * 8);

    hipMemsetAsync(vn_cnt, 0, N_VNS * 4, stream);
    hipMemsetAsync(cn_cnt, 0, N_CNS * 4, stream);
    hipMemsetAsync(vn_fill, 0, N_VNS * 4, stream);

    count_edges<<<(E + 255) / 256, 256, 0, stream>>>(vn_con, cn_con, E, vn_cnt, cn_cnt);
    scan_excl<<<1, 1024, 0, stream>>>(vn_cnt, N_VNS, vn_ptr);
    scan_excl<<<1, 1024, 0, stream>>>(cn_cnt, N_CNS, cn_ptr);
    fill_vn<<<(E + 255) / 256, 256, 0, stream>>>(vn_con, E, vn_ptr, vn_fill, vn_eids);
    sort_pack_vn<<<(N_VNS + 255) / 256, 256, 0, stream>>>(vn_ptr, vn_eids, cn_con, cn_ptr,
                                                          vn_pack);

    static bool attr_set = false;
    if (!attr_set) {
        hipFuncSetAttribute((const void*)decode,
                            hipFuncAttributeMaxDynamicSharedMemorySize, LDS_BYTES);
        attr_set = true;
    }
    decode<<<BATCH, 1024, LDS_BYTES, stream>>>(llr_ch, out, vn_pack);
}